// Round 6
// baseline (58279.913 us; speedup 1.0000x reference)
//
#include <hip/hip_runtime.h>
#include <hip/hip_bf16.h>
#include <type_traits>

#define T_    1000
#define NB    256
#define HH    64
#define GG    256

typedef float f32x4 __attribute__((ext_vector_type(4)));
typedef __bf16 bf16x8 __attribute__((ext_vector_type(8)));

__device__ __forceinline__ float fast_sigmoid(float x) {
    x = fminf(fmaxf(x, -30.f), 30.f);
    float e = __expf(-x);
    return __builtin_amdgcn_rcpf(1.f + e);
}
__device__ __forceinline__ float fast_tanh(float x) {
    x = fminf(fmaxf(x, -15.f), 15.f);
    float e = __expf(-2.f * x);
    return (1.f - e) * __builtin_amdgcn_rcpf(1.f + e);
}
__device__ __forceinline__ float bf2f(unsigned short u) {
    return __builtin_bit_cast(float, (unsigned)u << 16);
}

// ---------------------------------------------------------------- weight prep:
// w0f (2,256,32) f32 zero-padded from w_ih_first (2,256,22);
// bias (4,2,256) f32 = b_ih + b_hh. Everything else is read directly from d_in.
__global__ void prep_w(const float* __restrict__ wihf, const float* __restrict__ bih,
                       const float* __restrict__ bhh,
                       float* __restrict__ w0f, float* __restrict__ bias) {
    int i = blockIdx.x * 256 + threadIdx.x;
    if (i < 2 * GG * 32) {
        int k = i & 31, gd = i >> 5;
        w0f[i] = (k < 22) ? wihf[gd * 22 + k] : 0.f;
    }
    if (i < 4 * 2 * GG) bias[i] = bih[i] + bhh[i];
}

// ---------------------------------------------------------------- x prep:
// x (B,22,T) f32 -> xp (B,T,32) bf16, zero pad k>=22
__global__ __launch_bounds__(256) void prep_x(const float* __restrict__ x,
                                              __bf16* __restrict__ xp) {
    const int b = blockIdx.x;
    __shared__ float xs[22][104];
    for (int tc = 0; tc < 10; ++tc) {
        const int t0 = tc * 100;
        __syncthreads();
        for (int i = threadIdx.x; i < 22 * 100; i += 256) {
            int k = i / 100, t = i - k * 100;
            xs[k][t] = x[((size_t)b * 22 + k) * T_ + t0 + t];
        }
        __syncthreads();
        for (int i = threadIdx.x; i < 100 * 4; i += 256) {
            int t = i >> 2, p = i & 3;
            bf16x8 v;
            #pragma unroll
            for (int j = 0; j < 8; ++j) {
                int k = p * 8 + j;
                v[j] = (k < 22) ? (__bf16)xs[k][t] : (__bf16)0.f;
            }
            *(bf16x8*)(xp + ((size_t)b * T_ + t0 + t) * 32 + p * 8) = v;
        }
    }
}

// ---------------------------------------------------------------- pure-VALU fused scan:
// block=(b,dir) chain, 256 threads, thread = gate row g. Weights f32 in VGPRs.
// Per 8-step chunk: stage x-slice to LDS (f32). Per step: KIN+64 FMAs from LDS
// broadcast, activation to act[g], combine by threads<64, h f32 in LDS.
// TI = input plane scalar (bf16 or f32), TO = output plane scalar.
template<int KIN, typename TI, typename TO>
__global__ __launch_bounds__(256, 2) void scan_valu(
    const TI* __restrict__ in,       // (B,T,KIN)
    const float* __restrict__ wih,   // (2,256,KIN) f32
    const float* __restrict__ whh,   // (2,256,64) f32
    const float* __restrict__ bias,  // (2,256) f32
    TO* __restrict__ out)            // (B,T,128)
{
    const int dir = blockIdx.y, bb = blockIdx.x, g = threadIdx.x;
    __shared__ __align__(16) float xs[8][KIN];
    __shared__ __align__(16) float act[256];
    __shared__ __align__(16) float hs[2][64];

    float wk[KIN], wr[64];
    #pragma unroll 4
    for (int k = 0; k < KIN; ++k) wk[k] = wih[(dir * GG + g) * KIN + k];
    #pragma unroll 4
    for (int j = 0; j < 64; ++j)  wr[j] = whh[(dir * GG + g) * HH + j];
    const float bg = bias[dir * GG + g];
    const bool is_g = (g >= 128 && g < 192);  // tanh family, wave-uniform
    float c = 0.f;
    if (g < 64) hs[0][g] = 0.f;
    __syncthreads();

    float hreg[8];
    for (int ch = 0; ch < 125; ++ch) {
        // ---- stage 8 timesteps of input into LDS (as f32)
        if constexpr (KIN == 128) {
            int l = g * 4, u = l >> 7, k = l & 127;
            int s = ch * 8 + u, tt = dir ? (T_ - 1) - s : s;
            const TI* src = in + ((size_t)bb * T_ + tt) * 128 + k;
            f32x4 fv;
            if constexpr (std::is_same_v<TI, float>) {
                fv = *(const f32x4*)src;
            } else {
                ushort4 rv = *(const ushort4*)src;
                fv = (f32x4){bf2f(rv.x), bf2f(rv.y), bf2f(rv.z), bf2f(rv.w)};
            }
            *(f32x4*)&xs[u][k] = fv;
        } else {  // KIN == 32
            int u = g >> 5, k = g & 31;
            int s = ch * 8 + u, tt = dir ? (T_ - 1) - s : s;
            if constexpr (std::is_same_v<TI, float>)
                xs[u][k] = in[((size_t)bb * T_ + tt) * 32 + k];
            else
                xs[u][k] = bf2f(((const unsigned short*)in)[((size_t)bb * T_ + tt) * 32 + k]);
        }
        __syncthreads();

        // ---- 8 sequential steps
        #pragma unroll
        for (int u = 0; u < 8; ++u) {
            const int s = ch * 8 + u;
            const int p = s & 1;
            float a0 = bg, a1 = 0.f, a2 = 0.f, a3 = 0.f;
            #pragma unroll
            for (int k = 0; k < KIN; k += 4) {
                f32x4 xv = *(const f32x4*)&xs[u][k];
                a0 = fmaf(xv.x, wk[k + 0], a0);
                a1 = fmaf(xv.y, wk[k + 1], a1);
                a2 = fmaf(xv.z, wk[k + 2], a2);
                a3 = fmaf(xv.w, wk[k + 3], a3);
            }
            #pragma unroll
            for (int j = 0; j < 64; j += 4) {
                f32x4 hv = *(const f32x4*)&hs[p][j];
                a0 = fmaf(hv.x, wr[j + 0], a0);
                a1 = fmaf(hv.y, wr[j + 1], a1);
                a2 = fmaf(hv.z, wr[j + 2], a2);
                a3 = fmaf(hv.w, wr[j + 3], a3);
            }
            float a = (a0 + a1) + (a2 + a3);
            act[g] = is_g ? fast_tanh(a) : fast_sigmoid(a);
            __syncthreads();
            if (g < 64) {
                float iv = act[g], fv = act[64 + g], gv = act[128 + g], ov = act[192 + g];
                c = fmaf(fv, c, iv * gv);
                float hn = ov * fast_tanh(c);
                hs[p ^ 1][g] = hn;
                hreg[u] = hn;
            }
            __syncthreads();
        }
        // ---- flush 8 h values to the output plane
        if (g < 64) {
            #pragma unroll
            for (int u = 0; u < 8; ++u) {
                int s = ch * 8 + u, tt = dir ? (T_ - 1) - s : s;
                out[((size_t)bb * T_ + tt) * 128 + dir * HH + g] = (TO)hreg[u];
            }
        }
    }
}

// ---------------------------------------------------------------- head:
// out[b,o] = sum_j fin[b,999,j] * w_lin[o,j] + b_lin[o]  -> f32 output
template<typename TI>
__global__ __launch_bounds__(64) void head_kernel(
    const TI* __restrict__ fin, const float* __restrict__ wlin,
    const float* __restrict__ blin, float* __restrict__ outp) {
    const int b = blockIdx.x, tid = threadIdx.x;
    __shared__ float hv[128];
    #pragma unroll
    for (int rr = 0; rr < 2; ++rr) {
        int j = rr * 64 + tid;
        hv[j] = (float)fin[((size_t)b * T_ + (T_ - 1)) * 128 + j];
    }
    __syncthreads();
    if (tid < 54) {
        float a = blin[tid];
        #pragma unroll 4
        for (int j = 0; j < 128; ++j) a = fmaf(hv[j], wlin[tid * 128 + j], a);
        outp[b * 54 + tid] = a;   // FLOAT32 output — the reference returns f32
    }
}

extern "C" void kernel_launch(void* const* d_in, const int* in_sizes, int n_in,
                              void* d_out, int out_size, void* d_ws, size_t ws_size,
                              hipStream_t stream) {
    const float* x    = (const float*)d_in[0];  // (256,22,1000)
    const float* wihf = (const float*)d_in[1];  // (2,256,22)
    const float* wihr = (const float*)d_in[2];  // (3,2,256,128)
    const float* whh  = (const float*)d_in[3];  // (4,2,256,64)
    const float* bih  = (const float*)d_in[4];  // (4,2,256)
    const float* bhh  = (const float*)d_in[5];  // (4,2,256)
    const float* wlin = (const float*)d_in[6];  // (54,128)
    const float* blin = (const float*)d_in[7];  // (54,)
    float* outp = (float*)d_out;                // (256,54) f32

    char* ws = (char*)d_ws;
    const size_t PLF = (size_t)NB * T_ * 128 * sizeof(float);   // 131,072,000 B
    const size_t PLB = (size_t)NB * T_ * 128 * sizeof(__bf16);  //  65,536,000 B
    const bool f32p = ws_size >= 2 * PLF + (1 << 20);           // ~263 MB -> f32 planes

    const size_t PL = f32p ? PLF : PLB;
    char* smallw = ws + 2 * PL;
    float* w0f  = (float*)(smallw);            // 65,536 B (2,256,32)
    float* bias = (float*)(smallw + 65536);    //  8,192 B (4,2,256)
    __bf16* xp = (__bf16*)ws;  // (B,T,32) bf16, aliases plane A; dead before A is written

    prep_w<<<64, 256, 0, stream>>>(wihf, bih, bhh, w0f, bias);
    prep_x<<<NB, 256, 0, stream>>>(x, xp);

    const dim3 sgrid(NB, 2);
    // strides per layer: whh 2*256*64=32768 f32; bias 512 f32; wihr 2*256*128=65536 f32
    if (f32p) {
        float* A = (float*)ws;
        float* B = (float*)(ws + PLF);
        scan_valu<32, __bf16, float><<<sgrid, 256, 0, stream>>>(xp, w0f, whh, bias, B);
        scan_valu<128, float, float><<<sgrid, 256, 0, stream>>>(B, wihr,          whh + 32768, bias + 512,  A);
        scan_valu<128, float, float><<<sgrid, 256, 0, stream>>>(A, wihr + 65536,  whh + 65536, bias + 1024, B);
        scan_valu<128, float, float><<<sgrid, 256, 0, stream>>>(B, wihr + 131072, whh + 98304, bias + 1536, A);
        head_kernel<float><<<NB, 64, 0, stream>>>(A, wlin, blin, outp);
    } else {
        __bf16* A = (__bf16*)ws;
        __bf16* B = (__bf16*)(ws + PLB);
        scan_valu<32, __bf16, __bf16><<<sgrid, 256, 0, stream>>>(xp, w0f, whh, bias, B);
        scan_valu<128, __bf16, __bf16><<<sgrid, 256, 0, stream>>>(B, wihr,          whh + 32768, bias + 512,  A);
        scan_valu<128, __bf16, __bf16><<<sgrid, 256, 0, stream>>>(A, wihr + 65536,  whh + 65536, bias + 1024, B);
        scan_valu<128, __bf16, __bf16><<<sgrid, 256, 0, stream>>>(B, wihr + 131072, whh + 98304, bias + 1536, A);
        head_kernel<__bf16><<<NB, 64, 0, stream>>>(A, wlin, blin, outp);
    }
}

// Round 7
// 4442.036 us; speedup vs baseline: 13.1201x; 13.1201x over previous
//
#include <hip/hip_runtime.h>
#include <hip/hip_bf16.h>
#include <type_traits>

#define T_    1000
#define NB    256
#define HH    64
#define GG    256

typedef float f32x4 __attribute__((ext_vector_type(4)));
typedef __bf16 bf16x8 __attribute__((ext_vector_type(8)));

__device__ __forceinline__ float fast_sigmoid(float x) {
    x = fminf(fmaxf(x, -30.f), 30.f);
    float e = __expf(-x);
    return __builtin_amdgcn_rcpf(1.f + e);
}
__device__ __forceinline__ float fast_tanh(float x) {
    x = fminf(fmaxf(x, -15.f), 15.f);
    float e = __expf(-2.f * x);
    return (1.f - e) * __builtin_amdgcn_rcpf(1.f + e);
}
__device__ __forceinline__ float bf2f(unsigned short u) {
    return __builtin_bit_cast(float, (unsigned)u << 16);
}

// ---------------------------------------------------------------- weight prep:
// w0f (2,256,32) f32 zero-padded from w_ih_first (2,256,22);
// bias (4,2,256) f32 = b_ih + b_hh. Everything else is read directly from d_in.
__global__ void prep_w(const float* __restrict__ wihf, const float* __restrict__ bih,
                       const float* __restrict__ bhh,
                       float* __restrict__ w0f, float* __restrict__ bias) {
    int i = blockIdx.x * 256 + threadIdx.x;
    if (i < 2 * GG * 32) {
        int k = i & 31, gd = i >> 5;
        w0f[i] = (k < 22) ? wihf[gd * 22 + k] : 0.f;
    }
    if (i < 4 * 2 * GG) bias[i] = bih[i] + bhh[i];
}

// ---------------------------------------------------------------- x prep:
// x (B,22,T) f32 -> xp (B,T,32) bf16, zero pad k>=22
__global__ __launch_bounds__(256) void prep_x(const float* __restrict__ x,
                                              __bf16* __restrict__ xp) {
    const int b = blockIdx.x;
    __shared__ float xs[22][104];
    for (int tc = 0; tc < 10; ++tc) {
        const int t0 = tc * 100;
        __syncthreads();
        for (int i = threadIdx.x; i < 22 * 100; i += 256) {
            int k = i / 100, t = i - k * 100;
            xs[k][t] = x[((size_t)b * 22 + k) * T_ + t0 + t];
        }
        __syncthreads();
        for (int i = threadIdx.x; i < 100 * 4; i += 256) {
            int t = i >> 2, p = i & 3;
            bf16x8 v;
            #pragma unroll
            for (int j = 0; j < 8; ++j) {
                int k = p * 8 + j;
                v[j] = (k < 22) ? (__bf16)xs[k][t] : (__bf16)0.f;
            }
            *(bf16x8*)(xp + ((size_t)b * T_ + t0 + t) * 32 + p * 8) = v;
        }
    }
}

// ---------------------------------------------------------------- pure-VALU fused scan:
// block=(b,dir) chain, 256 threads, thread = gate row g. Weights f32 in VGPRs
// (FULL unroll + static indices -> register promotion; round-6's partial unroll
// demoted wk/wr to scratch: VGPR=20, 49 GB scratch traffic, VALUBusy 4%).
template<int KIN, typename TI, typename TO>
__global__ __launch_bounds__(256, 2) void scan_valu(
    const TI* __restrict__ in,       // (B,T,KIN)
    const float* __restrict__ wih,   // (2,256,KIN) f32
    const float* __restrict__ whh,   // (2,256,64) f32
    const float* __restrict__ bias,  // (2,256) f32
    TO* __restrict__ out)            // (B,T,128)
{
    const int dir = blockIdx.y, bb = blockIdx.x, g = threadIdx.x;
    __shared__ __align__(16) float xs[8][KIN];
    __shared__ __align__(16) float act[256];
    __shared__ __align__(16) float hs[2][64];

    float wk[KIN], wr[64];
    {
        const float* wp = wih + (size_t)(dir * GG + g) * KIN;
        #pragma unroll
        for (int k4 = 0; k4 < KIN / 4; ++k4) {
            f32x4 v = *(const f32x4*)(wp + k4 * 4);
            wk[k4 * 4 + 0] = v.x; wk[k4 * 4 + 1] = v.y;
            wk[k4 * 4 + 2] = v.z; wk[k4 * 4 + 3] = v.w;
        }
        const float* rp = whh + (size_t)(dir * GG + g) * HH;
        #pragma unroll
        for (int j4 = 0; j4 < 16; ++j4) {
            f32x4 v = *(const f32x4*)(rp + j4 * 4);
            wr[j4 * 4 + 0] = v.x; wr[j4 * 4 + 1] = v.y;
            wr[j4 * 4 + 2] = v.z; wr[j4 * 4 + 3] = v.w;
        }
    }
    const float bg = bias[dir * GG + g];
    const bool is_g = (g >= 128 && g < 192);  // tanh family, wave-uniform
    float c = 0.f;
    if (g < 64) hs[0][g] = 0.f;
    __syncthreads();

    float hreg[8];
    for (int ch = 0; ch < 125; ++ch) {
        // ---- stage 8 timesteps of input into LDS (as f32)
        if constexpr (KIN == 128) {
            int l = g * 4, u = l >> 7, k = l & 127;
            int s = ch * 8 + u, tt = dir ? (T_ - 1) - s : s;
            const TI* src = in + ((size_t)bb * T_ + tt) * 128 + k;
            f32x4 fv;
            if constexpr (std::is_same_v<TI, float>) {
                fv = *(const f32x4*)src;
            } else {
                ushort4 rv = *(const ushort4*)src;
                fv = (f32x4){bf2f(rv.x), bf2f(rv.y), bf2f(rv.z), bf2f(rv.w)};
            }
            *(f32x4*)&xs[u][k] = fv;
        } else {  // KIN == 32
            int u = g >> 5, k = g & 31;
            int s = ch * 8 + u, tt = dir ? (T_ - 1) - s : s;
            if constexpr (std::is_same_v<TI, float>)
                xs[u][k] = in[((size_t)bb * T_ + tt) * 32 + k];
            else
                xs[u][k] = bf2f(((const unsigned short*)in)[((size_t)bb * T_ + tt) * 32 + k]);
        }
        __syncthreads();

        // ---- 8 sequential steps
        #pragma unroll
        for (int u = 0; u < 8; ++u) {
            const int s = ch * 8 + u;
            const int p = s & 1;
            float a0 = bg, a1 = 0.f, a2 = 0.f, a3 = 0.f;
            #pragma unroll
            for (int k = 0; k < KIN; k += 4) {
                f32x4 xv = *(const f32x4*)&xs[u][k];
                a0 = fmaf(xv.x, wk[k + 0], a0);
                a1 = fmaf(xv.y, wk[k + 1], a1);
                a2 = fmaf(xv.z, wk[k + 2], a2);
                a3 = fmaf(xv.w, wk[k + 3], a3);
            }
            #pragma unroll
            for (int j = 0; j < 64; j += 4) {
                f32x4 hv = *(const f32x4*)&hs[p][j];
                a0 = fmaf(hv.x, wr[j + 0], a0);
                a1 = fmaf(hv.y, wr[j + 1], a1);
                a2 = fmaf(hv.z, wr[j + 2], a2);
                a3 = fmaf(hv.w, wr[j + 3], a3);
            }
            float a = (a0 + a1) + (a2 + a3);
            act[g] = is_g ? fast_tanh(a) : fast_sigmoid(a);
            __syncthreads();
            if (g < 64) {
                float iv = act[g], fv = act[64 + g], gv = act[128 + g], ov = act[192 + g];
                c = fmaf(fv, c, iv * gv);
                float hn = ov * fast_tanh(c);
                hs[p ^ 1][g] = hn;
                hreg[u] = hn;
            }
            __syncthreads();
        }
        // ---- flush 8 h values to the output plane
        if (g < 64) {
            #pragma unroll
            for (int u = 0; u < 8; ++u) {
                int s = ch * 8 + u, tt = dir ? (T_ - 1) - s : s;
                out[((size_t)bb * T_ + tt) * 128 + dir * HH + g] = (TO)hreg[u];
            }
        }
    }
}

// ---------------------------------------------------------------- head:
// out[b,o] = sum_j fin[b,999,j] * w_lin[o,j] + b_lin[o]  -> f32 output
template<typename TI>
__global__ __launch_bounds__(64) void head_kernel(
    const TI* __restrict__ fin, const float* __restrict__ wlin,
    const float* __restrict__ blin, float* __restrict__ outp) {
    const int b = blockIdx.x, tid = threadIdx.x;
    __shared__ float hv[128];
    #pragma unroll
    for (int rr = 0; rr < 2; ++rr) {
        int j = rr * 64 + tid;
        hv[j] = (float)fin[((size_t)b * T_ + (T_ - 1)) * 128 + j];
    }
    __syncthreads();
    if (tid < 54) {
        float a = blin[tid];
        #pragma unroll 4
        for (int j = 0; j < 128; ++j) a = fmaf(hv[j], wlin[tid * 128 + j], a);
        outp[b * 54 + tid] = a;   // FLOAT32 output — the reference returns f32
    }
}

extern "C" void kernel_launch(void* const* d_in, const int* in_sizes, int n_in,
                              void* d_out, int out_size, void* d_ws, size_t ws_size,
                              hipStream_t stream) {
    const float* x    = (const float*)d_in[0];  // (256,22,1000)
    const float* wihf = (const float*)d_in[1];  // (2,256,22)
    const float* wihr = (const float*)d_in[2];  // (3,2,256,128)
    const float* whh  = (const float*)d_in[3];  // (4,2,256,64)
    const float* bih  = (const float*)d_in[4];  // (4,2,256)
    const float* bhh  = (const float*)d_in[5];  // (4,2,256)
    const float* wlin = (const float*)d_in[6];  // (54,128)
    const float* blin = (const float*)d_in[7];  // (54,)
    float* outp = (float*)d_out;                // (256,54) f32

    char* ws = (char*)d_ws;
    const size_t PLF = (size_t)NB * T_ * 128 * sizeof(float);   // 131,072,000 B
    const size_t PLB = (size_t)NB * T_ * 128 * sizeof(__bf16);  //  65,536,000 B
    const bool f32p = ws_size >= 2 * PLF + (1 << 20);           // ~263 MB -> f32 planes

    const size_t PL = f32p ? PLF : PLB;
    char* smallw = ws + 2 * PL;
    float* w0f  = (float*)(smallw);            // 65,536 B (2,256,32)
    float* bias = (float*)(smallw + 65536);    //  8,192 B (4,2,256)
    __bf16* xp = (__bf16*)ws;  // (B,T,32) bf16, aliases plane A; dead before A is written

    prep_w<<<64, 256, 0, stream>>>(wihf, bih, bhh, w0f, bias);
    prep_x<<<NB, 256, 0, stream>>>(x, xp);

    const dim3 sgrid(NB, 2);
    // strides per layer: whh 2*256*64=32768 f32; bias 512 f32; wihr 2*256*128=65536 f32
    if (f32p) {
        float* A = (float*)ws;
        float* B = (float*)(ws + PLF);
        scan_valu<32, __bf16, float><<<sgrid, 256, 0, stream>>>(xp, w0f, whh, bias, B);
        scan_valu<128, float, float><<<sgrid, 256, 0, stream>>>(B, wihr,          whh + 32768, bias + 512,  A);
        scan_valu<128, float, float><<<sgrid, 256, 0, stream>>>(A, wihr + 65536,  whh + 65536, bias + 1024, B);
        scan_valu<128, float, float><<<sgrid, 256, 0, stream>>>(B, wihr + 131072, whh + 98304, bias + 1536, A);
        head_kernel<float><<<NB, 64, 0, stream>>>(A, wlin, blin, outp);
    } else {
        __bf16* A = (__bf16*)ws;
        __bf16* B = (__bf16*)(ws + PLB);
        scan_valu<32, __bf16, __bf16><<<sgrid, 256, 0, stream>>>(xp, w0f, whh, bias, B);
        scan_valu<128, __bf16, __bf16><<<sgrid, 256, 0, stream>>>(B, wihr,          whh + 32768, bias + 512,  A);
        scan_valu<128, __bf16, __bf16><<<sgrid, 256, 0, stream>>>(A, wihr + 65536,  whh + 65536, bias + 1024, B);
        scan_valu<128, __bf16, __bf16><<<sgrid, 256, 0, stream>>>(B, wihr + 131072, whh + 98304, bias + 1536, A);
        head_kernel<__bf16><<<NB, 64, 0, stream>>>(A, wlin, blin, outp);
    }
}

// Round 8
// 2635.126 us; speedup vs baseline: 22.1166x; 1.6857x over previous
//
#include <hip/hip_runtime.h>
#include <hip/hip_bf16.h>
#include <type_traits>

#define T_    1000
#define NB    256
#define HH    64
#define GG    256

typedef float f32x4 __attribute__((ext_vector_type(4)));
typedef __bf16 bf16x8 __attribute__((ext_vector_type(8)));

// Barrier that does NOT drain vmcnt (plain __syncthreads emits s_waitcnt vmcnt(0)
// which would stall on global h-stores and x-prefetch every step).
__device__ __forceinline__ void barrier_lds() {
    asm volatile("s_waitcnt lgkmcnt(0)\n\ts_barrier" ::: "memory");
}

__device__ __forceinline__ float fast_sigmoid(float x) {
    x = fminf(fmaxf(x, -30.f), 30.f);
    float e = __expf(-x);
    return __builtin_amdgcn_rcpf(1.f + e);
}
__device__ __forceinline__ float fast_tanh(float x) {
    x = fminf(fmaxf(x, -15.f), 15.f);
    float e = __expf(-2.f * x);
    return (1.f - e) * __builtin_amdgcn_rcpf(1.f + e);
}
__device__ __forceinline__ float bf2f(unsigned short u) {
    return __builtin_bit_cast(float, (unsigned)u << 16);
}

// ---------------------------------------------------------------- weight prep:
// w0H/w0L (2,256,32) bf16 hi/lo, zero-padded from w_ih_first (2,256,22)
// wrH (3,2,256,128) bf16-hi ; whH/whL (4,2,256,64) bf16 hi/lo
// bias (4,2,256) f32 = b_ih+b_hh ; w0f (2,256,32) f32 (VALU fallback path)
__global__ void prep_w(const float* __restrict__ wihf, const float* __restrict__ wihr,
                       const float* __restrict__ whh, const float* __restrict__ bih,
                       const float* __restrict__ bhh,
                       __bf16* __restrict__ w0H, __bf16* __restrict__ w0L,
                       __bf16* __restrict__ wrH, __bf16* __restrict__ whH,
                       __bf16* __restrict__ whL, float* __restrict__ bias,
                       float* __restrict__ w0f) {
    int i = blockIdx.x * 256 + threadIdx.x;
    if (i < 2 * GG * 32) {
        int k = i & 31, gd = i >> 5;
        float w = (k < 22) ? wihf[gd * 22 + k] : 0.f;
        __bf16 h = (__bf16)w;
        w0H[i] = h; w0L[i] = (__bf16)(w - (float)h);
        w0f[i] = w;
    }
    if (i < 3 * 2 * GG * 128) wrH[i] = (__bf16)wihr[i];
    if (i < 4 * 2 * GG * HH) {
        float w = whh[i];
        __bf16 h = (__bf16)w;
        whH[i] = h; whL[i] = (__bf16)(w - (float)h);
    }
    if (i < 4 * 2 * GG) bias[i] = bih[i] + bhh[i];
}

// ---------------------------------------------------------------- x prep:
// x (B,22,T) f32 -> xp (B,T,32), zero pad k>=22. TO = float (MFMA) or bf16 (fallback).
template<typename TO>
__global__ __launch_bounds__(256) void prep_x(const float* __restrict__ x,
                                              TO* __restrict__ xp) {
    const int b = blockIdx.x;
    __shared__ float xs[22][104];
    for (int tc = 0; tc < 10; ++tc) {
        const int t0 = tc * 100;
        __syncthreads();
        for (int i = threadIdx.x; i < 22 * 100; i += 256) {
            int k = i / 100, t = i - k * 100;
            xs[k][t] = x[((size_t)b * 22 + k) * T_ + t0 + t];
        }
        __syncthreads();
        for (int i = threadIdx.x; i < 100 * 4; i += 256) {
            int t = i >> 2, p = i & 3;
            if constexpr (std::is_same_v<TO, float>) {
                f32x4 v0, v1;
                #pragma unroll
                for (int j = 0; j < 4; ++j) {
                    int k0 = p * 8 + j, k1 = p * 8 + 4 + j;
                    v0[j] = (k0 < 22) ? xs[k0][t] : 0.f;
                    v1[j] = (k1 < 22) ? xs[k1][t] : 0.f;
                }
                *(f32x4*)(xp + ((size_t)b * T_ + t0 + t) * 32 + p * 8) = v0;
                *(f32x4*)(xp + ((size_t)b * T_ + t0 + t) * 32 + p * 8 + 4) = v1;
            } else {
                bf16x8 v;
                #pragma unroll
                for (int j = 0; j < 8; ++j) {
                    int k = p * 8 + j;
                    v[j] = (k < 22) ? (__bf16)xs[k][t] : (__bf16)0.f;
                }
                *(bf16x8*)(xp + ((size_t)b * T_ + t0 + t) * 32 + p * 8) = v;
            }
        }
    }
}

// ---------------------------------------------------------------- MFMA fused layer:
// One block = one (dir,batch) chain; 4 waves. Wave wv owns hidden slice
// j in [wv*16,wv*16+16) for all 4 gate families F (n-tiles {F*4+wv}).
// Per 8-step group: P = x-projection MFMA (A rows = steps; x f32 -> hi/lo bf16
// in-register, 2 passes vs wih-hi). Per step: h_{s-1} (bf16 hi/lo in LDS)
// replicated into ALL A rows -> fresh R; 3 passes (hH*WhH, hL*WhH, hH*WhL) x
// 2 ks x 4F = 24 MFMA. gates_u = P[row u]+R[row u]+bias at q=u>>2, r=u&3.
template<int KCH, bool WLO>
__global__ __launch_bounds__(256, 2) void fused_scan(
    const float* __restrict__ in,     // (B,T,KCH*32) f32
    const __bf16* __restrict__ wihH,  // (2,256,KCH*32) bf16 hi
    const __bf16* __restrict__ wihL,  // same, lo (used iff WLO)
    const __bf16* __restrict__ whhH,  // (2,256,64) bf16 hi
    const __bf16* __restrict__ whhL,  // (2,256,64) bf16 lo
    const float*  __restrict__ bias,  // (2,256) f32
    float* __restrict__ out)          // (B,T,128) f32
{
    const int dir = blockIdx.y, bb = blockIdx.x;
    const int tid = threadIdx.x;
    const int wv = tid >> 6, lane = tid & 63;
    const int j2 = lane & 15, q = lane >> 4;
    constexpr int KIN = KCH * 32;

    __shared__ __align__(16) __bf16 hbuf[2][2][64];  // [parity][hi/lo][j]
    __shared__ float cbuf[64];

    // B-layout weight fragments: lane holds B[k=q*8+e][n=j2] for row g.
    bf16x8 wf[4][KCH], wfl[4][WLO ? KCH : 1];
    bf16x8 whf[4][2], whl[4][2];
    float bgate[4];
    #pragma unroll
    for (int F = 0; F < 4; ++F) {
        const int g = (F * 4 + wv) * 16 + j2;
        bgate[F] = bias[dir * GG + g];
        #pragma unroll
        for (int ks = 0; ks < KCH; ++ks) {
            wf[F][ks] = *(const bf16x8*)(wihH + ((size_t)dir * GG + g) * KIN + ks * 32 + q * 8);
            if constexpr (WLO)
                wfl[F][ks] = *(const bf16x8*)(wihL + ((size_t)dir * GG + g) * KIN + ks * 32 + q * 8);
        }
        #pragma unroll
        for (int ks = 0; ks < 2; ++ks) {
            whf[F][ks] = *(const bf16x8*)(whhH + ((size_t)dir * GG + g) * HH + ks * 32 + q * 8);
            whl[F][ks] = *(const bf16x8*)(whhL + ((size_t)dir * GG + g) * HH + ks * 32 + q * 8);
        }
    }
    if (tid < 64) {
        cbuf[tid] = 0.f;
        hbuf[1][0][tid] = (__bf16)0.f;
        hbuf[1][1][tid] = (__bf16)0.f;
    }
    __syncthreads();

    const int m8 = lane & 7;   // A-row (step in group); rows 8..15 duplicate
    f32x4 xst[2 * KCH];
    auto issue_x = [&](int grp) {
        int s = grp * 8 + m8;
        int tt = dir ? (T_ - 1) - s : s;
        const float* p = in + ((size_t)bb * T_ + tt) * KIN + q * 8;
        #pragma unroll
        for (int ks = 0; ks < KCH; ++ks) {
            xst[2 * ks] = *(const f32x4*)(p + ks * 32);
            xst[2 * ks + 1] = *(const f32x4*)(p + ks * 32 + 4);
        }
    };
    issue_x(0);

    const size_t outch = (size_t)bb * T_ * 128 + dir * HH + wv * 16 + j2;
    float hsave[8];

    for (int grp = 0; grp < 125; ++grp) {
        // ---- split staged f32 x into bf16 hi/lo fragments
        bf16x8 xh[KCH], xl[KCH];
        #pragma unroll
        for (int ks = 0; ks < KCH; ++ks)
            #pragma unroll
            for (int e = 0; e < 8; ++e) {
                float f = xst[2 * ks + (e >> 2)][e & 3];
                __bf16 h = (__bf16)f;
                xh[ks][e] = h;
                xl[ks][e] = (__bf16)(f - (float)h);
            }
        // ---- group init: input projection into P (rows 0..7 = steps)
        f32x4 P[4];
        #pragma unroll
        for (int F = 0; F < 4; ++F) P[F] = (f32x4){0.f, 0.f, 0.f, 0.f};
        #pragma unroll
        for (int F = 0; F < 4; ++F) {
            #pragma unroll
            for (int ks = 0; ks < KCH; ++ks)
                P[F] = __builtin_amdgcn_mfma_f32_16x16x32_bf16(xh[ks], wf[F][ks], P[F], 0, 0, 0);
            #pragma unroll
            for (int ks = 0; ks < KCH; ++ks)
                P[F] = __builtin_amdgcn_mfma_f32_16x16x32_bf16(xl[ks], wf[F][ks], P[F], 0, 0, 0);
            if constexpr (WLO)
                #pragma unroll
                for (int ks = 0; ks < KCH; ++ks)
                    P[F] = __builtin_amdgcn_mfma_f32_16x16x32_bf16(xh[ks], wfl[F][ks], P[F], 0, 0, 0);
        }
        if (grp + 1 < 125) issue_x(grp + 1);  // prefetch next group's x

        // ---- 8 sequential steps
        #pragma unroll
        for (int u = 0; u < 8; ++u) {
            const int s = grp * 8 + u;
            const int rp = (s + 1) & 1;
            float cold = cbuf[wv * 16 + j2];
            bf16x8 ah[2], al[2];
            #pragma unroll
            for (int ks = 0; ks < 2; ++ks) {
                ah[ks] = *(const bf16x8*)&hbuf[rp][0][ks * 32 + q * 8];
                al[ks] = *(const bf16x8*)&hbuf[rp][1][ks * 32 + q * 8];
            }
            f32x4 R[4];
            #pragma unroll
            for (int F = 0; F < 4; ++F) R[F] = (f32x4){0.f, 0.f, 0.f, 0.f};
            #pragma unroll
            for (int F = 0; F < 4; ++F) {
                R[F] = __builtin_amdgcn_mfma_f32_16x16x32_bf16(ah[0], whf[F][0], R[F], 0, 0, 0);
                R[F] = __builtin_amdgcn_mfma_f32_16x16x32_bf16(ah[1], whf[F][1], R[F], 0, 0, 0);
                R[F] = __builtin_amdgcn_mfma_f32_16x16x32_bf16(al[0], whf[F][0], R[F], 0, 0, 0);
                R[F] = __builtin_amdgcn_mfma_f32_16x16x32_bf16(al[1], whf[F][1], R[F], 0, 0, 0);
                R[F] = __builtin_amdgcn_mfma_f32_16x16x32_bf16(ah[0], whl[F][0], R[F], 0, 0, 0);
                R[F] = __builtin_amdgcn_mfma_f32_16x16x32_bf16(ah[1], whl[F][1], R[F], 0, 0, 0);
            }
            const int r = u & 3;  // gates at C row u: q==u>>2, reg r
            float iv = P[0][r] + R[0][r] + bgate[0];
            float fv = P[1][r] + R[1][r] + bgate[1];
            float gv = P[2][r] + R[2][r] + bgate[2];
            float ov = P[3][r] + R[3][r] + bgate[3];
            float cn = fast_sigmoid(fv) * cold + fast_sigmoid(iv) * fast_tanh(gv);
            float hn = fast_sigmoid(ov) * fast_tanh(cn);
            if (q == (u >> 2)) {
                cbuf[wv * 16 + j2] = cn;
                __bf16 hi = (__bf16)hn;
                hbuf[s & 1][0][wv * 16 + j2] = hi;
                hbuf[s & 1][1][wv * 16 + j2] = (__bf16)(hn - (float)hi);
                hsave[u] = hn;
            }
            barrier_lds();
        }
        // ---- flush 8 f32 h's (stores drain lazily; no vmcnt barrier)
        #pragma unroll
        for (int u = 0; u < 8; ++u) {
            if (q == (u >> 2)) {
                const int s = grp * 8 + u;
                const int tt = dir ? (T_ - 1) - s : s;
                out[outch + (size_t)tt * 128] = hsave[u];
            }
        }
    }
}

// ---------------------------------------------------------------- VALU fallback scan
// (round-7 proven; runs only if ws_size < f32-plane requirement)
template<int KIN, typename TI, typename TO>
__global__ __launch_bounds__(256, 2) void scan_valu(
    const TI* __restrict__ in, const float* __restrict__ wih,
    const float* __restrict__ whh, const float* __restrict__ bias,
    TO* __restrict__ out)
{
    const int dir = blockIdx.y, bb = blockIdx.x, g = threadIdx.x;
    __shared__ __align__(16) float xs[8][KIN];
    __shared__ __align__(16) float act[256];
    __shared__ __align__(16) float hs[2][64];

    float wk[KIN], wr[64];
    {
        const float* wp = wih + (size_t)(dir * GG + g) * KIN;
        #pragma unroll
        for (int k4 = 0; k4 < KIN / 4; ++k4) {
            f32x4 v = *(const f32x4*)(wp + k4 * 4);
            wk[k4 * 4 + 0] = v.x; wk[k4 * 4 + 1] = v.y;
            wk[k4 * 4 + 2] = v.z; wk[k4 * 4 + 3] = v.w;
        }
        const float* rp = whh + (size_t)(dir * GG + g) * HH;
        #pragma unroll
        for (int j4 = 0; j4 < 16; ++j4) {
            f32x4 v = *(const f32x4*)(rp + j4 * 4);
            wr[j4 * 4 + 0] = v.x; wr[j4 * 4 + 1] = v.y;
            wr[j4 * 4 + 2] = v.z; wr[j4 * 4 + 3] = v.w;
        }
    }
    const float bg = bias[dir * GG + g];
    const bool is_g = (g >= 128 && g < 192);
    float c = 0.f;
    if (g < 64) hs[0][g] = 0.f;
    __syncthreads();

    float hreg[8];
    for (int ch = 0; ch < 125; ++ch) {
        if constexpr (KIN == 128) {
            int l = g * 4, u = l >> 7, k = l & 127;
            int s = ch * 8 + u, tt = dir ? (T_ - 1) - s : s;
            const TI* src = in + ((size_t)bb * T_ + tt) * 128 + k;
            f32x4 fv;
            if constexpr (std::is_same_v<TI, float>) fv = *(const f32x4*)src;
            else {
                ushort4 rv = *(const ushort4*)src;
                fv = (f32x4){bf2f(rv.x), bf2f(rv.y), bf2f(rv.z), bf2f(rv.w)};
            }
            *(f32x4*)&xs[u][k] = fv;
        } else {
            int u = g >> 5, k = g & 31;
            int s = ch * 8 + u, tt = dir ? (T_ - 1) - s : s;
            if constexpr (std::is_same_v<TI, float>)
                xs[u][k] = in[((size_t)bb * T_ + tt) * 32 + k];
            else
                xs[u][k] = bf2f(((const unsigned short*)in)[((size_t)bb * T_ + tt) * 32 + k]);
        }
        __syncthreads();
        #pragma unroll
        for (int u = 0; u < 8; ++u) {
            const int p = (ch * 8 + u) & 1;
            float a0 = bg, a1 = 0.f, a2 = 0.f, a3 = 0.f;
            #pragma unroll
            for (int k = 0; k < KIN; k += 4) {
                f32x4 xv = *(const f32x4*)&xs[u][k];
                a0 = fmaf(xv.x, wk[k + 0], a0); a1 = fmaf(xv.y, wk[k + 1], a1);
                a2 = fmaf(xv.z, wk[k + 2], a2); a3 = fmaf(xv.w, wk[k + 3], a3);
            }
            #pragma unroll
            for (int j = 0; j < 64; j += 4) {
                f32x4 hv = *(const f32x4*)&hs[p][j];
                a0 = fmaf(hv.x, wr[j + 0], a0); a1 = fmaf(hv.y, wr[j + 1], a1);
                a2 = fmaf(hv.z, wr[j + 2], a2); a3 = fmaf(hv.w, wr[j + 3], a3);
            }
            float a = (a0 + a1) + (a2 + a3);
            act[g] = is_g ? fast_tanh(a) : fast_sigmoid(a);
            __syncthreads();
            if (g < 64) {
                float iv = act[g], fv = act[64 + g], gv = act[128 + g], ov = act[192 + g];
                c = fmaf(fv, c, iv * gv);
                float hn = ov * fast_tanh(c);
                hs[p ^ 1][g] = hn;
                hreg[u] = hn;
            }
            __syncthreads();
        }
        if (g < 64) {
            #pragma unroll
            for (int u = 0; u < 8; ++u) {
                int s = ch * 8 + u, tt = dir ? (T_ - 1) - s : s;
                out[((size_t)bb * T_ + tt) * 128 + dir * HH + g] = (TO)hreg[u];
            }
        }
    }
}

// ---------------------------------------------------------------- head (f32 out)
template<typename TI>
__global__ __launch_bounds__(64) void head_kernel(
    const TI* __restrict__ fin, const float* __restrict__ wlin,
    const float* __restrict__ blin, float* __restrict__ outp) {
    const int b = blockIdx.x, tid = threadIdx.x;
    __shared__ float hv[128];
    #pragma unroll
    for (int rr = 0; rr < 2; ++rr) {
        int j = rr * 64 + tid;
        hv[j] = (float)fin[((size_t)b * T_ + (T_ - 1)) * 128 + j];
    }
    __syncthreads();
    if (tid < 54) {
        float a = blin[tid];
        #pragma unroll 4
        for (int j = 0; j < 128; ++j) a = fmaf(hv[j], wlin[tid * 128 + j], a);
        outp[b * 54 + tid] = a;
    }
}

extern "C" void kernel_launch(void* const* d_in, const int* in_sizes, int n_in,
                              void* d_out, int out_size, void* d_ws, size_t ws_size,
                              hipStream_t stream) {
    const float* x    = (const float*)d_in[0];
    const float* wihf = (const float*)d_in[1];
    const float* wihr = (const float*)d_in[2];
    const float* whh  = (const float*)d_in[3];
    const float* bih  = (const float*)d_in[4];
    const float* bhh  = (const float*)d_in[5];
    const float* wlin = (const float*)d_in[6];
    const float* blin = (const float*)d_in[7];
    float* outp = (float*)d_out;

    char* ws = (char*)d_ws;
    const size_t PLF = (size_t)NB * T_ * 128 * sizeof(float);   // 131,072,000 B
    const size_t PLB = (size_t)NB * T_ * 128 * sizeof(__bf16);
    const bool f32p = ws_size >= 2 * PLF + (1 << 20);           // proven true (r7 FETCH)

    const size_t PL = f32p ? PLF : PLB;
    char* sw = ws + 2 * PL;
    __bf16* w0H  = (__bf16*)(sw);             //  32,768 B
    __bf16* w0L  = (__bf16*)(sw + 32768);     //  32,768 B
    __bf16* wrH  = (__bf16*)(sw + 65536);     // 393,216 B
    __bf16* whH  = (__bf16*)(sw + 458752);    // 262,144 B
    __bf16* whL  = (__bf16*)(sw + 720896);    // 262,144 B
    float*  bias = (float*) (sw + 983040);    //   8,192 B
    float*  w0f  = (float*) (sw + 991232);    //  65,536 B (fallback)

    prep_w<<<768, 256, 0, stream>>>(wihf, wihr, whh, bih, bhh,
                                    w0H, w0L, wrH, whH, whL, bias, w0f);

    const dim3 sgrid(NB, 2);
    // per-layer strides: whH/whL 2*256*64=32768 bf16; bias 512 f32; wrH 2*256*128=65536 bf16
    if (f32p) {
        float* A = (float*)ws;
        float* B = (float*)(ws + PLF);
        float* xp = B;  // (B,T,32) f32 plane aliases B; consumed before B is written
        prep_x<float><<<NB, 256, 0, stream>>>(x, xp);
        fused_scan<1, true><<<sgrid, 256, 0, stream>>>(xp, w0H, w0L, whH, whL, bias, A);
        fused_scan<4, false><<<sgrid, 256, 0, stream>>>(A, wrH, nullptr,
            whH + 32768, whL + 32768, bias + 512, B);
        fused_scan<4, false><<<sgrid, 256, 0, stream>>>(B, wrH + 65536, nullptr,
            whH + 65536, whL + 65536, bias + 1024, A);
        fused_scan<4, false><<<sgrid, 256, 0, stream>>>(A, wrH + 131072, nullptr,
            whH + 98304, whL + 98304, bias + 1536, B);
        head_kernel<float><<<NB, 64, 0, stream>>>(B, wlin, blin, outp);
    } else {
        __bf16* A = (__bf16*)ws;
        __bf16* B = (__bf16*)(ws + PLB);
        __bf16* xp = (__bf16*)ws;  // aliases A; dead before A written
        prep_x<__bf16><<<NB, 256, 0, stream>>>(x, xp);
        scan_valu<32, __bf16, __bf16><<<sgrid, 256, 0, stream>>>(xp, w0f, whh, bias, B);
        scan_valu<128, __bf16, __bf16><<<sgrid, 256, 0, stream>>>(B, wihr,          whh + 32768, bias + 512,  A);
        scan_valu<128, __bf16, __bf16><<<sgrid, 256, 0, stream>>>(A, wihr + 65536,  whh + 65536, bias + 1024, B);
        scan_valu<128, __bf16, __bf16><<<sgrid, 256, 0, stream>>>(B, wihr + 131072, whh + 98304, bias + 1536, A);
        head_kernel<__bf16><<<NB, 64, 0, stream>>>(A, wlin, blin, outp);
    }
}

// Round 9
// 1914.822 us; speedup vs baseline: 30.4362x; 1.3762x over previous
//
#include <hip/hip_runtime.h>
#include <hip/hip_bf16.h>
#include <type_traits>

#define T_    1000
#define NB    256
#define HH    64
#define GG    256

typedef float f32x4 __attribute__((ext_vector_type(4)));
typedef __bf16 bf16x8 __attribute__((ext_vector_type(8)));

// Barrier that does NOT drain vmcnt (plain __syncthreads emits s_waitcnt vmcnt(0)
// which would stall on global h-stores and x-prefetch every step).
__device__ __forceinline__ void barrier_lds() {
    asm volatile("s_waitcnt lgkmcnt(0)\n\ts_barrier" ::: "memory");
}

// Gate pre-activations are bounded (|w|~0.1, |h|<=1, bf16 inputs) -> no clamps
// needed for sigmoid; tanh needs only the lower clamp (exp overflow -> NaN).
__device__ __forceinline__ float fast_sigmoid(float x) {
    float e = __expf(-x);
    return __builtin_amdgcn_rcpf(1.f + e);
}
__device__ __forceinline__ float fast_tanh(float x) {
    x = fmaxf(x, -15.f);
    float e = __expf(-2.f * x);
    return (1.f - e) * __builtin_amdgcn_rcpf(1.f + e);
}
__device__ __forceinline__ float bf2f(unsigned short u) {
    return __builtin_bit_cast(float, (unsigned)u << 16);
}

// ---------------------------------------------------------------- weight prep
__global__ void prep_w(const float* __restrict__ wihf, const float* __restrict__ wihr,
                       const float* __restrict__ whh, const float* __restrict__ bih,
                       const float* __restrict__ bhh,
                       __bf16* __restrict__ w0H, __bf16* __restrict__ w0L,
                       __bf16* __restrict__ wrH, __bf16* __restrict__ whH,
                       __bf16* __restrict__ whL, float* __restrict__ bias,
                       float* __restrict__ w0f) {
    int i = blockIdx.x * 256 + threadIdx.x;
    if (i < 2 * GG * 32) {
        int k = i & 31, gd = i >> 5;
        float w = (k < 22) ? wihf[gd * 22 + k] : 0.f;
        __bf16 h = (__bf16)w;
        w0H[i] = h; w0L[i] = (__bf16)(w - (float)h);
        w0f[i] = w;
    }
    if (i < 3 * 2 * GG * 128) wrH[i] = (__bf16)wihr[i];
    if (i < 4 * 2 * GG * HH) {
        float w = whh[i];
        __bf16 h = (__bf16)w;
        whH[i] = h; whL[i] = (__bf16)(w - (float)h);
    }
    if (i < 4 * 2 * GG) bias[i] = bih[i] + bhh[i];
}

// ---------------------------------------------------------------- x prep:
// x (B,22,T) f32 -> xp (B,T,32), zero pad k>=22
template<typename TO>
__global__ __launch_bounds__(256) void prep_x(const float* __restrict__ x,
                                              TO* __restrict__ xp) {
    const int b = blockIdx.x;
    __shared__ float xs[22][104];
    for (int tc = 0; tc < 10; ++tc) {
        const int t0 = tc * 100;
        __syncthreads();
        for (int i = threadIdx.x; i < 22 * 100; i += 256) {
            int k = i / 100, t = i - k * 100;
            xs[k][t] = x[((size_t)b * 22 + k) * T_ + t0 + t];
        }
        __syncthreads();
        for (int i = threadIdx.x; i < 100 * 4; i += 256) {
            int t = i >> 2, p = i & 3;
            if constexpr (std::is_same_v<TO, float>) {
                f32x4 v0, v1;
                #pragma unroll
                for (int j = 0; j < 4; ++j) {
                    int k0 = p * 8 + j, k1 = p * 8 + 4 + j;
                    v0[j] = (k0 < 22) ? xs[k0][t] : 0.f;
                    v1[j] = (k1 < 22) ? xs[k1][t] : 0.f;
                }
                *(f32x4*)(xp + ((size_t)b * T_ + t0 + t) * 32 + p * 8) = v0;
                *(f32x4*)(xp + ((size_t)b * T_ + t0 + t) * 32 + p * 8 + 4) = v1;
            } else {
                bf16x8 v;
                #pragma unroll
                for (int j = 0; j < 8; ++j) {
                    int k = p * 8 + j;
                    v[j] = (k < 22) ? (__bf16)xs[k][t] : (__bf16)0.f;
                }
                *(bf16x8*)(xp + ((size_t)b * T_ + t0 + t) * 32 + p * 8) = v;
            }
        }
    }
}

// ---------------------------------------------------------------- MFMA fused layer, 2 chains/block:
// Block = (batch pair b0,b0+1; dir). A rows 0-7 = chain0 (b0) steps, rows 8-15 =
// chain1 (b0+1) steps — weights (B operand) shared since same direction. Per
// group: P = x-projection (each row its chain's x_t). Per step: h of chain c
// replicated into rows 8c..8c+7 -> R rows 8c+u = h_c.Whh^T. Gates for chain ch
// at lanes (q&1)==(u>>2), ch=q>>1: row q*4+(u&3) = 8ch+u. MFMA issue is
// F-innermost (4 independent accumulator chains back-to-back).
template<int KCH, bool WLO>
__global__ __launch_bounds__(256, 1) void fused_scan2(
    const float* __restrict__ in,     // (B,T,KCH*32) f32
    const __bf16* __restrict__ wihH,  // (2,256,KCH*32) bf16 hi
    const __bf16* __restrict__ wihL,  // same, lo (iff WLO)
    const __bf16* __restrict__ whhH,  // (2,256,64) bf16 hi
    const __bf16* __restrict__ whhL,  // (2,256,64) bf16 lo
    const float*  __restrict__ bias,  // (2,256) f32
    float* __restrict__ out)          // (B,T,128) f32
{
    const int dir = blockIdx.y;
    const int b0 = blockIdx.x * 2;
    const int tid = threadIdx.x;
    const int wv = tid >> 6, lane = tid & 63;
    const int j2 = lane & 15, q = lane >> 4;
    const int ch_l = j2 >> 3;          // chain of this lane's A-row
    const int u_l = j2 & 7;            // step-in-group of this lane's A-row
    constexpr int KIN = KCH * 32;

    __shared__ __align__(16) __bf16 hbuf[2][2][2][64]; // [parity][chain][hi/lo][j]
    __shared__ float cbuf[2][64];

    bf16x8 wf[4][KCH], wfl[4][WLO ? KCH : 1];
    bf16x8 whf[4][2], whl[4][2];
    float bgate[4];
    #pragma unroll
    for (int F = 0; F < 4; ++F) {
        const int g = (F * 4 + wv) * 16 + j2;
        bgate[F] = bias[dir * GG + g];
        #pragma unroll
        for (int ks = 0; ks < KCH; ++ks) {
            wf[F][ks] = *(const bf16x8*)(wihH + ((size_t)dir * GG + g) * KIN + ks * 32 + q * 8);
            if constexpr (WLO)
                wfl[F][ks] = *(const bf16x8*)(wihL + ((size_t)dir * GG + g) * KIN + ks * 32 + q * 8);
        }
        #pragma unroll
        for (int ks = 0; ks < 2; ++ks) {
            whf[F][ks] = *(const bf16x8*)(whhH + ((size_t)dir * GG + g) * HH + ks * 32 + q * 8);
            whl[F][ks] = *(const bf16x8*)(whhL + ((size_t)dir * GG + g) * HH + ks * 32 + q * 8);
        }
    }
    if (tid < 64) {
        cbuf[0][tid] = 0.f; cbuf[1][tid] = 0.f;
        hbuf[1][0][0][tid] = (__bf16)0.f; hbuf[1][0][1][tid] = (__bf16)0.f;
        hbuf[1][1][0][tid] = (__bf16)0.f; hbuf[1][1][1][tid] = (__bf16)0.f;
    }
    __syncthreads();

    f32x4 xst[2 * KCH];
    auto issue_x = [&](int grp) {
        int s = grp * 8 + u_l;
        int tt = dir ? (T_ - 1) - s : s;
        const float* p = in + ((size_t)(b0 + ch_l) * T_ + tt) * KIN + q * 8;
        #pragma unroll
        for (int ks = 0; ks < KCH; ++ks) {
            xst[2 * ks] = *(const f32x4*)(p + ks * 32);
            xst[2 * ks + 1] = *(const f32x4*)(p + ks * 32 + 4);
        }
    };
    issue_x(0);

    float hsave[8];
    float creg = 0.f;

    for (int grp = 0; grp < 125; ++grp) {
        // split staged f32 x into bf16 hi/lo fragments
        bf16x8 xh[KCH], xl[KCH];
        #pragma unroll
        for (int ks = 0; ks < KCH; ++ks)
            #pragma unroll
            for (int e = 0; e < 8; ++e) {
                float f = xst[2 * ks + (e >> 2)][e & 3];
                __bf16 h = (__bf16)f;
                xh[ks][e] = h;
                xl[ks][e] = (__bf16)(f - (float)h);
            }
        // group init: input projection (F-innermost interleave)
        f32x4 P[4];
        #pragma unroll
        for (int F = 0; F < 4; ++F) P[F] = (f32x4){0.f, 0.f, 0.f, 0.f};
        #pragma unroll
        for (int ks = 0; ks < KCH; ++ks)
            #pragma unroll
            for (int F = 0; F < 4; ++F)
                P[F] = __builtin_amdgcn_mfma_f32_16x16x32_bf16(xh[ks], wf[F][ks], P[F], 0, 0, 0);
        #pragma unroll
        for (int ks = 0; ks < KCH; ++ks)
            #pragma unroll
            for (int F = 0; F < 4; ++F)
                P[F] = __builtin_amdgcn_mfma_f32_16x16x32_bf16(xl[ks], wf[F][ks], P[F], 0, 0, 0);
        if constexpr (WLO) {
            #pragma unroll
            for (int ks = 0; ks < KCH; ++ks)
                #pragma unroll
                for (int F = 0; F < 4; ++F)
                    P[F] = __builtin_amdgcn_mfma_f32_16x16x32_bf16(xh[ks], wfl[F][ks], P[F], 0, 0, 0);
        }
        if (grp + 1 < 125) issue_x(grp + 1);

        // 8 sequential steps
        #pragma unroll
        for (int u = 0; u < 8; ++u) {
            const int s = grp * 8 + u;
            const int rp = (s + 1) & 1;
            // A rows 8c..8c+7 <- h of chain c (this lane: ch_l)
            bf16x8 ah[2], al[2];
            #pragma unroll
            for (int ks = 0; ks < 2; ++ks) {
                ah[ks] = *(const bf16x8*)&hbuf[rp][ch_l][0][ks * 32 + q * 8];
                al[ks] = *(const bf16x8*)&hbuf[rp][ch_l][1][ks * 32 + q * 8];
            }
            f32x4 R[4];
            #pragma unroll
            for (int F = 0; F < 4; ++F) R[F] = (f32x4){0.f, 0.f, 0.f, 0.f};
            #pragma unroll
            for (int F = 0; F < 4; ++F)
                R[F] = __builtin_amdgcn_mfma_f32_16x16x32_bf16(ah[0], whf[F][0], R[F], 0, 0, 0);
            #pragma unroll
            for (int F = 0; F < 4; ++F)
                R[F] = __builtin_amdgcn_mfma_f32_16x16x32_bf16(ah[1], whf[F][1], R[F], 0, 0, 0);
            #pragma unroll
            for (int F = 0; F < 4; ++F)
                R[F] = __builtin_amdgcn_mfma_f32_16x16x32_bf16(al[0], whf[F][0], R[F], 0, 0, 0);
            #pragma unroll
            for (int F = 0; F < 4; ++F)
                R[F] = __builtin_amdgcn_mfma_f32_16x16x32_bf16(al[1], whf[F][1], R[F], 0, 0, 0);
            #pragma unroll
            for (int F = 0; F < 4; ++F)
                R[F] = __builtin_amdgcn_mfma_f32_16x16x32_bf16(ah[0], whl[F][0], R[F], 0, 0, 0);
            #pragma unroll
            for (int F = 0; F < 4; ++F)
                R[F] = __builtin_amdgcn_mfma_f32_16x16x32_bf16(ah[1], whl[F][1], R[F], 0, 0, 0);

            const int r = u & 3;
            const int ch = q >> 1;
            const bool owner = ((q & 1) == (u >> 2));
            // c: register within each 4-step half; LDS handoff at half boundaries
            float cold = (u == 0 || u == 4) ? cbuf[ch][wv * 16 + j2] : creg;
            float iv = P[0][r] + R[0][r] + bgate[0];
            float fv = P[1][r] + R[1][r] + bgate[1];
            float gv = P[2][r] + R[2][r] + bgate[2];
            float ov = P[3][r] + R[3][r] + bgate[3];
            float cn = fast_sigmoid(fv) * cold + fast_sigmoid(iv) * fast_tanh(gv);
            float hn = fast_sigmoid(ov) * fast_tanh(cn);
            creg = cn;
            if (owner) {
                if (u == 3 || u == 7) cbuf[ch][wv * 16 + j2] = cn;
                __bf16 hi = (__bf16)hn;
                hbuf[s & 1][ch][0][wv * 16 + j2] = hi;
                hbuf[s & 1][ch][1][wv * 16 + j2] = (__bf16)(hn - (float)hi);
                hsave[u] = hn;
            }
            barrier_lds();
        }
        // flush 8 f32 h's per chain (stores drain lazily; no vmcnt barrier)
        #pragma unroll
        for (int u = 0; u < 8; ++u) {
            if ((q & 1) == (u >> 2)) {
                const int s = grp * 8 + u;
                const int tt = dir ? (T_ - 1) - s : s;
                out[((size_t)(b0 + (q >> 1)) * T_ + tt) * 128 + dir * HH + wv * 16 + j2] = hsave[u];
            }
        }
    }
}

// ---------------------------------------------------------------- VALU fallback scan
// (round-7 proven; runs only if ws_size < f32-plane requirement)
template<int KIN, typename TI, typename TO>
__global__ __launch_bounds__(256, 2) void scan_valu(
    const TI* __restrict__ in, const float* __restrict__ wih,
    const float* __restrict__ whh, const float* __restrict__ bias,
    TO* __restrict__ out)
{
    const int dir = blockIdx.y, bb = blockIdx.x, g = threadIdx.x;
    __shared__ __align__(16) float xs[8][KIN];
    __shared__ __align__(16) float act[256];
    __shared__ __align__(16) float hs[2][64];

    float wk[KIN], wr[64];
    {
        const float* wp = wih + (size_t)(dir * GG + g) * KIN;
        #pragma unroll
        for (int k4 = 0; k4 < KIN / 4; ++k4) {
            f32x4 v = *(const f32x4*)(wp + k4 * 4);
            wk[k4 * 4 + 0] = v.x; wk[k4 * 4 + 1] = v.y;
            wk[k4 * 4 + 2] = v.z; wk[k4 * 4 + 3] = v.w;
        }
        const float* rp = whh + (size_t)(dir * GG + g) * HH;
        #pragma unroll
        for (int j4 = 0; j4 < 16; ++j4) {
            f32x4 v = *(const f32x4*)(rp + j4 * 4);
            wr[j4 * 4 + 0] = v.x; wr[j4 * 4 + 1] = v.y;
            wr[j4 * 4 + 2] = v.z; wr[j4 * 4 + 3] = v.w;
        }
    }
    const float bg = bias[dir * GG + g];
    const bool is_g = (g >= 128 && g < 192);
    float c = 0.f;
    if (g < 64) hs[0][g] = 0.f;
    __syncthreads();

    float hreg[8];
    for (int ch = 0; ch < 125; ++ch) {
        if constexpr (KIN == 128) {
            int l = g * 4, u = l >> 7, k = l & 127;
            int s = ch * 8 + u, tt = dir ? (T_ - 1) - s : s;
            const TI* src = in + ((size_t)bb * T_ + tt) * 128 + k;
            f32x4 fv;
            if constexpr (std::is_same_v<TI, float>) fv = *(const f32x4*)src;
            else {
                ushort4 rv = *(const ushort4*)src;
                fv = (f32x4){bf2f(rv.x), bf2f(rv.y), bf2f(rv.z), bf2f(rv.w)};
            }
            *(f32x4*)&xs[u][k] = fv;
        } else {
            int u = g >> 5, k = g & 31;
            int s = ch * 8 + u, tt = dir ? (T_ - 1) - s : s;
            if constexpr (std::is_same_v<TI, float>)
                xs[u][k] = in[((size_t)bb * T_ + tt) * 32 + k];
            else
                xs[u][k] = bf2f(((const unsigned short*)in)[((size_t)bb * T_ + tt) * 32 + k]);
        }
        __syncthreads();
        #pragma unroll
        for (int u = 0; u < 8; ++u) {
            const int p = (ch * 8 + u) & 1;
            float a0 = bg, a1 = 0.f, a2 = 0.f, a3 = 0.f;
            #pragma unroll
            for (int k = 0; k < KIN; k += 4) {
                f32x4 xv = *(const f32x4*)&xs[u][k];
                a0 = fmaf(xv.x, wk[k + 0], a0); a1 = fmaf(xv.y, wk[k + 1], a1);
                a2 = fmaf(xv.z, wk[k + 2], a2); a3 = fmaf(xv.w, wk[k + 3], a3);
            }
            #pragma unroll
            for (int j = 0; j < 64; j += 4) {
                f32x4 hv = *(const f32x4*)&hs[p][j];
                a0 = fmaf(hv.x, wr[j + 0], a0); a1 = fmaf(hv.y, wr[j + 1], a1);
                a2 = fmaf(hv.z, wr[j + 2], a2); a3 = fmaf(hv.w, wr[j + 3], a3);
            }
            float a = (a0 + a1) + (a2 + a3);
            act[g] = is_g ? fast_tanh(a) : fast_sigmoid(a);
            __syncthreads();
            if (g < 64) {
                float iv = act[g], fv = act[64 + g], gv = act[128 + g], ov = act[192 + g];
                c = fmaf(fv, c, iv * gv);
                float hn = ov * fast_tanh(c);
                hs[p ^ 1][g] = hn;
                hreg[u] = hn;
            }
            __syncthreads();
        }
        if (g < 64) {
            #pragma unroll
            for (int u = 0; u < 8; ++u) {
                int s = ch * 8 + u, tt = dir ? (T_ - 1) - s : s;
                out[((size_t)bb * T_ + tt) * 128 + dir * HH + g] = (TO)hreg[u];
            }
        }
    }
}

// ---------------------------------------------------------------- head (f32 out)
template<typename TI>
__global__ __launch_bounds__(64) void head_kernel(
    const TI* __restrict__ fin, const float* __restrict__ wlin,
    const float* __restrict__ blin, float* __restrict__ outp) {
    const int b = blockIdx.x, tid = threadIdx.x;
    __shared__ float hv[128];
    #pragma unroll
    for (int rr = 0; rr < 2; ++rr) {
        int j = rr * 64 + tid;
        hv[j] = (float)fin[((size_t)b * T_ + (T_ - 1)) * 128 + j];
    }
    __syncthreads();
    if (tid < 54) {
        float a = blin[tid];
        #pragma unroll 4
        for (int j = 0; j < 128; ++j) a = fmaf(hv[j], wlin[tid * 128 + j], a);
        outp[b * 54 + tid] = a;
    }
}

extern "C" void kernel_launch(void* const* d_in, const int* in_sizes, int n_in,
                              void* d_out, int out_size, void* d_ws, size_t ws_size,
                              hipStream_t stream) {
    const float* x    = (const float*)d_in[0];
    const float* wihf = (const float*)d_in[1];
    const float* wihr = (const float*)d_in[2];
    const float* whh  = (const float*)d_in[3];
    const float* bih  = (const float*)d_in[4];
    const float* bhh  = (const float*)d_in[5];
    const float* wlin = (const float*)d_in[6];
    const float* blin = (const float*)d_in[7];
    float* outp = (float*)d_out;

    char* ws = (char*)d_ws;
    const size_t PLF = (size_t)NB * T_ * 128 * sizeof(float);   // 131,072,000 B
    const size_t PLB = (size_t)NB * T_ * 128 * sizeof(__bf16);
    const bool f32p = ws_size >= 2 * PLF + (1 << 20);           // proven true (r7/r8 FETCH)

    const size_t PL = f32p ? PLF : PLB;
    char* sw = ws + 2 * PL;
    __bf16* w0H  = (__bf16*)(sw);             //  32,768 B
    __bf16* w0L  = (__bf16*)(sw + 32768);     //  32,768 B
    __bf16* wrH  = (__bf16*)(sw + 65536);     // 393,216 B
    __bf16* whH  = (__bf16*)(sw + 458752);    // 262,144 B
    __bf16* whL  = (__bf16*)(sw + 720896);    // 262,144 B
    float*  bias = (float*) (sw + 983040);    //   8,192 B
    float*  w0f  = (float*) (sw + 991232);    //  65,536 B (fallback)

    prep_w<<<768, 256, 0, stream>>>(wihf, wihr, whh, bih, bhh,
                                    w0H, w0L, wrH, whH, whL, bias, w0f);

    if (f32p) {
        float* A = (float*)ws;
        float* B = (float*)(ws + PLF);
        float* xp = B;  // (B,T,32) f32 aliases B; consumed before B is written
        prep_x<float><<<NB, 256, 0, stream>>>(x, xp);
        const dim3 sgrid(NB / 2, 2);
        fused_scan2<1, true><<<sgrid, 256, 0, stream>>>(xp, w0H, w0L, whH, whL, bias, A);
        fused_scan2<4, false><<<sgrid, 256, 0, stream>>>(A, wrH, nullptr,
            whH + 32768, whL + 32768, bias + 512, B);
        fused_scan2<4, false><<<sgrid, 256, 0, stream>>>(B, wrH + 65536, nullptr,
            whH + 65536, whL + 65536, bias + 1024, A);
        fused_scan2<4, false><<<sgrid, 256, 0, stream>>>(A, wrH + 131072, nullptr,
            whH + 98304, whL + 98304, bias + 1536, B);
        head_kernel<float><<<NB, 64, 0, stream>>>(B, wlin, blin, outp);
    } else {
        __bf16* A = (__bf16*)ws;
        __bf16* B = (__bf16*)(ws + PLB);
        __bf16* xp = (__bf16*)ws;  // aliases A; dead before A written
        prep_x<__bf16><<<NB, 256, 0, stream>>>(x, xp);
        const dim3 vgrid(NB, 2);
        scan_valu<32, __bf16, __bf16><<<vgrid, 256, 0, stream>>>(xp, w0f, whh, bias, B);
        scan_valu<128, __bf16, __bf16><<<vgrid, 256, 0, stream>>>(B, wihr,          whh + 32768, bias + 512,  A);
        scan_valu<128, __bf16, __bf16><<<vgrid, 256, 0, stream>>>(A, wihr + 65536,  whh + 65536, bias + 1024, B);
        scan_valu<128, __bf16, __bf16><<<vgrid, 256, 0, stream>>>(B, wihr + 131072, whh + 98304, bias + 1536, A);
        head_kernel<__bf16><<<NB, 64, 0, stream>>>(A, wlin, blin, outp);
    }
}